// Round 3
// baseline (353.395 us; speedup 1.0000x reference)
//
#include <hip/hip_runtime.h>

#define NE 40943
#define NR 18
#define ED 200
#define KWC 9
#define OC 32
#define WOUT 192
#define KOC 288      // KW*OC
#define KH 224       // padded K (ED 200 -> 224) for gemm2
#define G2_LD 40     // 32 + 8 pad (bf16 elems)
#define EP_LD 132    // epilogue f32 leading dim (128 + 4 pad)

typedef unsigned short u16;
typedef unsigned int u32;
typedef __bf16 bf16x8 __attribute__((ext_vector_type(8)));
typedef float f32x4 __attribute__((ext_vector_type(4)));
typedef float f32x4u __attribute__((ext_vector_type(4), aligned(4)));
typedef u16 u16x8 __attribute__((ext_vector_type(8)));

__device__ __forceinline__ u16 f2bf(float f) {
  u32 u = __builtin_bit_cast(u32, f);
  u32 r = (u + 0x7fffu + ((u >> 16) & 1u)) >> 16;
  return (u16)r;
}

// KrT[j*32+o][rel] = sum_d R[rel][d] * W1[d][j*32+o] + b1[j*32+o]   (288 x 18, f32)
__global__ void prep_k_kernel(const float* __restrict__ R,
                              const float* __restrict__ W1,
                              const float* __restrict__ b1,
                              float* __restrict__ KrT) {
  int rel = blockIdx.x;
  int j = threadIdx.x;  // 0..287
  float acc = b1[j];
  const float* rrow = R + rel * ED;
#pragma unroll 8
  for (int d = 0; d < ED; ++d) acc += rrow[d] * W1[d * KOC + j];
  KrT[j * NR + rel] = acc;
}

// C[r][p][d] = sum_{j,o; 0<=p-j<192} KrT[j*32+o][r] * W2[(o*192+(p-j))*200 + d]
__global__ __launch_bounds__(256) void build_c_kernel(const float* __restrict__ KrT,
                                                      const float* __restrict__ W2,
                                                      float* __restrict__ C) {
  int p = blockIdx.x;   // 0..199
  int d = threadIdx.x;  // active < 200
  int jlo = p > (WOUT - 1) ? p - (WOUT - 1) : 0;
  int jhi = p < (KWC - 1) ? p : (KWC - 1);
  if (d < ED) {
    float acc[NR];
#pragma unroll
    for (int r = 0; r < NR; ++r) acc[r] = 0.f;
    for (int j = jlo; j <= jhi; ++j) {
      int w = p - j;
      const float* w2base = W2 + (size_t)w * ED + d;  // += o*192*200
      const float* kb = KrT + (j * OC) * NR;          // block-uniform -> s_load
#pragma unroll
      for (int o = 0; o < OC; ++o) {
        float w2v = w2base[(size_t)o * WOUT * ED];
#pragma unroll
        for (int r = 0; r < NR; ++r) acc[r] += kb[o * NR + r] * w2v;
      }
    }
#pragma unroll
    for (int r = 0; r < NR; ++r) C[((size_t)r * ED + p) * ED + d] = acc[r];
  }
}

// Hb[b][d] = bf16(relu(sum_p E[e1_idx[b]][p] * C[r_idx[b]][p][d] + b2[d])), pad d in [200,224) = 0
__global__ __launch_bounds__(256) void h_kernel(const int* __restrict__ e1_idx,
                                                const int* __restrict__ r_idx,
                                                const float* __restrict__ E,
                                                const float* __restrict__ C,
                                                const float* __restrict__ b2,
                                                u16* __restrict__ Hb) {
  __shared__ float e1s[ED];
  int b = blockIdx.x;
  int t = threadIdx.x;
  if (t < ED) e1s[t] = E[(size_t)e1_idx[b] * ED + t];
  __syncthreads();
  int r = r_idx[b];
  const float* Cr = C + (size_t)r * ED * ED;
  if (t < KH) {
    float acc = 0.f;
    if (t < ED) {
#pragma unroll 8
      for (int p = 0; p < ED; ++p) acc += e1s[p] * Cr[(size_t)p * ED + t];
      acc += b2[t];
      acc = acc > 0.f ? acc : 0.f;
    }
    Hb[(size_t)b * KH + t] = (t < ED) ? f2bf(acc) : (u16)0;
  }
}

// out[b][n] = sum_d Hb[b][d] * bf16(E[n][d]) + bias[n]   (f32 out)
// E converted f32->bf16 in-register during staging (conv_e fused away).
__global__ __launch_bounds__(256) void gemm2_kernel(
    const u16* __restrict__ Hb,  // [1024][224] bf16
    const float* __restrict__ E, // [40943][200] f32
    const float* __restrict__ bias,
    float* __restrict__ out) {
  __shared__ __align__(16) char smem[20480];  // lA(10240) + lB(10240); reused as 32x132 f32 epilogue
  u16* lA = (u16*)smem;
  u16* lB = lA + 128 * G2_LD;
  const int t = threadIdx.x;
  const int m0 = blockIdx.y * 128;
  const int n0 = blockIdx.x * 128;
  const int wave = t >> 6, lane = t & 63;
  const int wm = (wave >> 1) * 64, wn = (wave & 1) * 64;
  const int lr = lane & 15, lq = lane >> 4;
  f32x4 zero = {0.f, 0.f, 0.f, 0.f};
  f32x4 acc[4][4];
#pragma unroll
  for (int i = 0; i < 4; ++i)
#pragma unroll
    for (int j = 0; j < 4; ++j) acc[i][j] = zero;

  for (int k0 = 0; k0 < KH; k0 += 32) {
#pragma unroll
    for (int s = 0; s < 2; ++s) {
      int v = t + s * 256;
      int r = v >> 2;           // 0..127
      int c8 = (v & 3) * 8;     // 0,8,16,24
      *(u16x8*)(lA + r * G2_LD + c8) = *(const u16x8*)(Hb + (size_t)(m0 + r) * KH + k0 + c8);
      int gr = n0 + r;
      u16x8 bv = {0, 0, 0, 0, 0, 0, 0, 0};
      int kc = k0 + c8;
      if (gr < NE && kc < ED) {  // kc in {0..192}; 200%8==0 -> never straddles the edge
        const float* ep = E + (size_t)gr * ED + kc;
        f32x4 v0 = *(const f32x4*)ep;
        f32x4 v1 = *(const f32x4*)(ep + 4);
        bv[0] = f2bf(v0[0]); bv[1] = f2bf(v0[1]); bv[2] = f2bf(v0[2]); bv[3] = f2bf(v0[3]);
        bv[4] = f2bf(v1[0]); bv[5] = f2bf(v1[1]); bv[6] = f2bf(v1[2]); bv[7] = f2bf(v1[3]);
      }
      *(u16x8*)(lB + r * G2_LD + c8) = bv;
    }
    __syncthreads();
    bf16x8 af[4], bfv[4];
#pragma unroll
    for (int mi = 0; mi < 4; ++mi)
      af[mi] = *(const bf16x8*)(lA + (wm + mi * 16 + lr) * G2_LD + lq * 8);
#pragma unroll
    for (int ni = 0; ni < 4; ++ni)
      bfv[ni] = *(const bf16x8*)(lB + (wn + ni * 16 + lr) * G2_LD + lq * 8);
#pragma unroll
    for (int mi = 0; mi < 4; ++mi)
#pragma unroll
      for (int ni = 0; ni < 4; ++ni)
        acc[mi][ni] = __builtin_amdgcn_mfma_f32_16x16x32_bf16(af[mi], bfv[ni], acc[mi][ni], 0, 0, 0);
    __syncthreads();
  }

  // Epilogue: LDS transpose -> contiguous 512B-per-row stores
  float* lsF = (float*)smem;
  const int rL = t >> 3;        // 0..31
  const int cg = (t & 7) * 16;  // 0..112
#pragma unroll
  for (int mi = 0; mi < 4; ++mi) {
    __syncthreads();
#pragma unroll
    for (int ni = 0; ni < 4; ++ni)
#pragma unroll
      for (int i = 0; i < 4; ++i)
        lsF[((wave >> 1) * 16 + lq * 4 + i) * EP_LD + wn + ni * 16 + lr] = acc[mi][ni][i];
    __syncthreads();
    int grow = m0 + (rL >> 4) * 64 + mi * 16 + (rL & 15);
    int gc0 = n0 + cg;
#pragma unroll
    for (int kq = 0; kq < 4; ++kq) {
      int gc = gc0 + kq * 4;
      f32x4 v = *(const f32x4*)(lsF + rL * EP_LD + cg + kq * 4);
      if (gc + 3 < NE) {
        f32x4 bb = *(const f32x4*)(bias + gc);
        *(f32x4u*)(out + (size_t)grow * NE + gc) = v + bb;
      } else {
#pragma unroll
        for (int e = 0; e < 4; ++e)
          if (gc + e < NE) out[(size_t)grow * NE + gc + e] = v[e] + bias[gc + e];
      }
    }
  }
}

extern "C" void kernel_launch(void* const* d_in, const int* in_sizes, int n_in,
                              void* d_out, int out_size, void* d_ws, size_t ws_size,
                              hipStream_t stream) {
  const int* e1_idx = (const int*)d_in[0];
  const int* r_idx = (const int*)d_in[1];
  const float* W1 = (const float*)d_in[2];
  const float* b1 = (const float*)d_in[3];
  const float* W2 = (const float*)d_in[4];
  const float* b2 = (const float*)d_in[5];
  const float* bias_logits = (const float*)d_in[6];
  const float* E = (const float*)d_in[7];
  const float* R = (const float*)d_in[8];
  float* out = (float*)d_out;

  char* ws = (char*)d_ws;
  float* KrT = (float*)ws;                 // 288*18*4 = 20,736
  float* C = (float*)(ws + 32768);         // 18*200*200*4 = 2,880,000
  u16* Hb = (u16*)(ws + 32768 + 2880000);  // 1024*224*2 = 458,752

  prep_k_kernel<<<dim3(NR), dim3(KOC), 0, stream>>>(R, W1, b1, KrT);
  build_c_kernel<<<dim3(ED), dim3(256), 0, stream>>>(KrT, W2, C);
  h_kernel<<<dim3(1024), dim3(256), 0, stream>>>(e1_idx, r_idx, E, C, b2, Hb);
  gemm2_kernel<<<dim3((NE + 127) / 128, 8), dim3(256), 0, stream>>>(Hb, E, bias_logits, out);
}